// Round 15
// baseline (238.770 us; speedup 1.0000x reference)
//
#include <hip/hip_runtime.h>
#include <hip/hip_bf16.h>

#define D128 128
#define NEG_SLOPE 0.2f

typedef __attribute__((ext_vector_type(8))) short bf16x8;
typedef __attribute__((ext_vector_type(4))) float f32x4;

__device__ inline float bf2f(unsigned short u) {
    return __uint_as_float(((unsigned)u) << 16);
}
__device__ inline unsigned short f2bf(float f) {  // RTNE
    unsigned u = __float_as_uint(f);
    unsigned r = (u + 0x7fffu + ((u >> 16) & 1u)) >> 16;
    return (unsigned short)r;
}

// ---------------------------------------------------------------------------
// CSR build
// ---------------------------------------------------------------------------
__global__ void zero_int_kernel(int* __restrict__ p, int n) {
    int i = blockIdx.x * blockDim.x + threadIdx.x;
    if (i < n) p[i] = 0;
}

__global__ void count_kernel(const int* __restrict__ dst, int E, int* __restrict__ cnt) {
    int e = blockIdx.x * blockDim.x + threadIdx.x;
    if (e < E) atomicAdd(&cnt[dst[e]], 1);
}

#define SB 256
#define SCAN_CHUNK 2048  // SB * 8

__global__ __launch_bounds__(SB) void scan_local_kernel(const int* __restrict__ cnt,
                                                        int* __restrict__ off,
                                                        int* __restrict__ partials, int N) {
    __shared__ int lds[SB];
    const int b = blockIdx.x;
    const int t = threadIdx.x;
    const int base = b * SCAN_CHUNK + t * 8;
    int v[8];
    int s = 0;
#pragma unroll
    for (int j = 0; j < 8; ++j) {
        int i = base + j;
        v[j] = (i < N) ? cnt[i] : 0;
        s += v[j];
    }
    lds[t] = s;
    __syncthreads();
    for (int d = 1; d < SB; d <<= 1) {
        int y = (t >= d) ? lds[t - d] : 0;
        __syncthreads();
        lds[t] += y;
        __syncthreads();
    }
    int pref = lds[t] - s;
#pragma unroll
    for (int j = 0; j < 8; ++j) {
        int i = base + j;
        if (i < N) off[i] = pref;
        pref += v[j];
    }
    if (t == SB - 1) partials[b] = lds[t];
}

__global__ __launch_bounds__(64) void scan_partials_kernel(int* __restrict__ partials,
                                                           int* __restrict__ pp, int NB,
                                                           int* __restrict__ off, int N) {
    __shared__ int lds[64];
    int t = threadIdx.x;
    int v = (t < NB) ? partials[t] : 0;
    lds[t] = v;
    __syncthreads();
    for (int d = 1; d < 64; d <<= 1) {
        int y = (t >= d) ? lds[t - d] : 0;
        __syncthreads();
        lds[t] += y;
        __syncthreads();
    }
    pp[t] = lds[t] - v;
    if (t == 63) off[N] = lds[63];
}

__global__ void scan_add_kernel(int* __restrict__ off, int* __restrict__ cur,
                                const int* __restrict__ pp, int N) {
    int i = blockIdx.x * blockDim.x + threadIdx.x;
    if (i < N) {
        int o = off[i] + pp[i / SCAN_CHUNK];
        off[i] = o;
        cur[i] = o;
    }
}

__global__ void fill_kernel(const int* __restrict__ src, const int* __restrict__ dst, int E,
                            int* __restrict__ cur, int* __restrict__ csr_src) {
    int e = blockIdx.x * blockDim.x + threadIdx.x;
    if (e < E) {
        int p = atomicAdd(&cur[dst[e]], 1);
        csr_src[p] = src[e];
    }
}

// ---------------------------------------------------------------------------
// W repack into MFMA B-fragment order, split hi/lo bf16 — all 3 GAT layers
// in one dispatch (blockIdx.y selects the weight matrix).
// ---------------------------------------------------------------------------
__global__ __launch_bounds__(256) void wrepack3_kernel(const float* __restrict__ W0,
                                                       const float* __restrict__ W1,
                                                       const float* __restrict__ W2,
                                                       unsigned short* __restrict__ wb0,
                                                       unsigned short* __restrict__ wb1,
                                                       unsigned short* __restrict__ wb2) {
    const float* W = (blockIdx.y == 0) ? W0 : (blockIdx.y == 1) ? W1 : W2;
    unsigned short* Wb = (blockIdx.y == 0) ? wb0 : (blockIdx.y == 1) ? wb1 : wb2;
    int i = blockIdx.x * 256 + threadIdx.x;  // 0..16383
    if (i >= 16384) return;
    int j = i & 7;
    int l = (i >> 3) & 63;
    int kk = (i >> 9) & 3;
    int ct = i >> 11;
    int k = kk * 32 + ((l >> 4) & 3) * 8 + j;
    int c = ct * 16 + (l & 15);
    float w = W[k * 128 + c];
    unsigned short hi = f2bf(w);
    unsigned short lo = f2bf(w - bf2f(hi));
    Wb[i] = hi;
    Wb[16384 + i] = lo;
}

// bf16-hi-only repack for the two MLP weights in one dispatch.
__global__ __launch_bounds__(256) void wrepack_mlp_kernel(const float* __restrict__ mw1,
                                                          unsigned short* __restrict__ w1f,
                                                          const float* __restrict__ mw2,
                                                          unsigned short* __restrict__ w2f) {
    const int y = blockIdx.y;
    const float* W = y ? mw2 : mw1;
    unsigned short* Wf = y ? w2f : w1f;
    const int K = y ? 128 : 256, C = y ? 64 : 128;
    int total = K * C;
    int i = blockIdx.x * 256 + threadIdx.x;
    if (i >= total) return;
    int j = i & 7;
    int l = (i >> 3) & 63;
    int kkct = i >> 9;
    int KK = K >> 5;
    int kk = kkct % KK;
    int ct = kkct / KK;
    int k = kk * 32 + (l >> 4) * 8 + j;
    int c = ct * 16 + (l & 15);
    Wf[i] = f2bf(W[k * C + c]);
}

// ---------------------------------------------------------------------------
// MFMA GEMM (split-bf16 ~ fp32 accuracy) fused with attention scalars.
// 8 waves/block, 128 rows/block, W fragments staged in LDS.
// ---------------------------------------------------------------------------
template <int H, bool SPLIT>
__global__ __launch_bounds__(512) void gemm_mfma_kernel(const float* __restrict__ X0,
                                                        const float* __restrict__ X1, int split,
                                                        const unsigned short* __restrict__ Wb,
                                                        const float* __restrict__ att_s,
                                                        const float* __restrict__ att_d,
                                                        unsigned short* __restrict__ hb,
                                                        float* __restrict__ a_s,
                                                        float* __restrict__ a_d, int N) {
    __shared__ unsigned short wlds[32768];  // 64 KB: hi [0,16384), lo [16384,32768)
    const int t = threadIdx.x;
    const int lane = t & 63;
    const int wave = t >> 6;
    const int row0 = blockIdx.x * 128 + wave * 16;

    for (int i = t; i < 4096; i += 512)
        ((int4*)wlds)[i] = ((const int4*)Wb)[i];

    const int lr = lane & 15;
    const int lk = lane >> 4;

    int arow = row0 + lr;
    if (arow >= N) arow = N - 1;  // clamp; padded rows never stored
    const float* xrow;
    if (SPLIT)
        xrow = (arow < split) ? &X0[(size_t)arow * 128] : &X1[(size_t)(arow - split) * 128];
    else
        xrow = &X0[(size_t)arow * 128];

    bf16x8 ahi[4], alo[4];
#pragma unroll
    for (int kk = 0; kk < 4; ++kk) {
        const float* ap = &xrow[kk * 32 + lk * 8];
        float4 v0 = *(const float4*)ap;
        float4 v1 = *(const float4*)(ap + 4);
        float f[8] = {v0.x, v0.y, v0.z, v0.w, v1.x, v1.y, v1.z, v1.w};
#pragma unroll
        for (int j = 0; j < 8; ++j) {
            unsigned short hi = f2bf(f[j]);
            unsigned short lo = f2bf(f[j] - bf2f(hi));
            ((short*)&ahi[kk])[j] = (short)hi;
            ((short*)&alo[kk])[j] = (short)lo;
        }
    }

    f32x4 acc[8];
#pragma unroll
    for (int ct = 0; ct < 8; ++ct) acc[ct] = (f32x4){0.f, 0.f, 0.f, 0.f};

    __syncthreads();

#pragma unroll
    for (int kk = 0; kk < 4; ++kk) {
#pragma unroll
        for (int ct = 0; ct < 8; ++ct) {
            const int fo = ((ct * 4 + kk) * 64 + lane) * 8;
            bf16x8 bhi = *(const bf16x8*)&wlds[fo];
            bf16x8 blo = *(const bf16x8*)&wlds[16384 + fo];
            acc[ct] = __builtin_amdgcn_mfma_f32_16x16x32_bf16(ahi[kk], bhi, acc[ct], 0, 0, 0);
            acc[ct] = __builtin_amdgcn_mfma_f32_16x16x32_bf16(ahi[kk], blo, acc[ct], 0, 0, 0);
            acc[ct] = __builtin_amdgcn_mfma_f32_16x16x32_bf16(alo[kk], bhi, acc[ct], 0, 0, 0);
        }
    }

    float ps[4][H], pd[4][H];
#pragma unroll
    for (int r = 0; r < 4; ++r)
#pragma unroll
        for (int h = 0; h < H; ++h) { ps[r][h] = 0.f; pd[r][h] = 0.f; }

#pragma unroll
    for (int ct = 0; ct < 8; ++ct) {
        float as_c = att_s[ct * 16 + lr];
        float ad_c = att_d[ct * 16 + lr];
        const int h = (ct * H) >> 3;
#pragma unroll
        for (int r = 0; r < 4; ++r) {
            float v = acc[ct][r];
            int row = row0 + lk * 4 + r;
            if (row < N) hb[(size_t)row * 128 + ct * 16 + lr] = f2bf(v);
            ps[r][h] += v * as_c;
            pd[r][h] += v * ad_c;
        }
    }

#pragma unroll
    for (int m = 1; m < 16; m <<= 1) {
#pragma unroll
        for (int r = 0; r < 4; ++r)
#pragma unroll
            for (int h = 0; h < H; ++h) {
                ps[r][h] += __shfl_xor(ps[r][h], m);
                pd[r][h] += __shfl_xor(pd[r][h], m);
            }
    }
    if (lr == 0) {
#pragma unroll
        for (int r = 0; r < 4; ++r) {
            int row = row0 + lk * 4 + r;
            if (row < N) {
                if (H == 4) {
                    *(float4*)&a_s[(size_t)row * 4] =
                        make_float4(ps[r][0], ps[r][1], ps[r][2], ps[r][3]);
                    *(float4*)&a_d[(size_t)row * 4] =
                        make_float4(pd[r][0], pd[r][1], pd[r][2], pd[r][3]);
                } else {
                    a_s[row] = ps[r][0];
                    a_d[row] = pd[r][0];
                }
            }
        }
    }
}

// ---------------------------------------------------------------------------
// aggregation + bias + ELU + residual + LayerNorm, softmax numerator inline.
// CHANNEL-SPLIT: 16 lanes per node (8 channels, dwordx4 gathers), 4 nodes
// per wave, 16 nodes per 256-thr block.  4-deep edge unroll: 4 independent
// {a_s gather + h row gather} pairs in flight; 2-deep + 1 tails.  No LDS.
// ---------------------------------------------------------------------------
template <int H, bool RES>
__global__ __launch_bounds__(256) void agg_kernel(const unsigned short* __restrict__ hb,
                                                  const float* __restrict__ a_s,
                                                  const float* __restrict__ a_d,
                                                  const int* __restrict__ off,
                                                  const int* __restrict__ csr_src,
                                                  const float* __restrict__ xprev,
                                                  const float* __restrict__ bias,
                                                  const float* __restrict__ ln_g,
                                                  const float* __restrict__ ln_b,
                                                  float* __restrict__ xout, int N) {
    const int t = threadIdx.x;
    const int l16 = t & 15;                 // lane within node group
    const int gbase = t & 48;               // group's base lane within wave
    const int n = blockIdx.x * 16 + (t >> 4);
    if (n >= N) return;
    const int c8 = l16 * 8;                 // first of this lane's 8 channels
    const int head = (c8 * H) >> 7;         // c8 / (128/H)
    const int base = off[n];
    const int deg = off[n + 1] - base;
    const float adn = a_d[(size_t)n * H + head];

    float accA[8], accB[8];
#pragma unroll
    for (int j = 0; j < 8; ++j) { accA[j] = 0.f; accB[j] = 0.f; }
    float psA = 0.f, psB = 0.f;

#define ACC8(ACC, P, HV)                                                     \
    ACC[0] = fmaf(P, bf2f((unsigned short)HV.x), ACC[0]);                    \
    ACC[1] = fmaf(P, bf2f((unsigned short)(HV.x >> 16)), ACC[1]);            \
    ACC[2] = fmaf(P, bf2f((unsigned short)HV.y), ACC[2]);                    \
    ACC[3] = fmaf(P, bf2f((unsigned short)(HV.y >> 16)), ACC[3]);            \
    ACC[4] = fmaf(P, bf2f((unsigned short)HV.z), ACC[4]);                    \
    ACC[5] = fmaf(P, bf2f((unsigned short)(HV.z >> 16)), ACC[5]);            \
    ACC[6] = fmaf(P, bf2f((unsigned short)HV.w), ACC[6]);                    \
    ACC[7] = fmaf(P, bf2f((unsigned short)(HV.w >> 16)), ACC[7]);

#define LEAKY_EXP(AS)                                                        \
    ({ float lg_ = (AS) + adn;                                               \
       lg_ = lg_ >= 0.f ? lg_ : NEG_SLOPE * lg_;                             \
       expf(lg_); })

    for (int e0 = 0; e0 < deg; e0 += 16) {
        const int ce = min(16, deg - e0);
        int myidx = 0;
        if (l16 < ce) myidx = csr_src[base + e0 + l16];
        int e = 0;
        for (; e + 3 < ce; e += 4) {
            int s0 = __shfl(myidx, gbase + e);
            int s1 = __shfl(myidx, gbase + e + 1);
            int s2 = __shfl(myidx, gbase + e + 2);
            int s3 = __shfl(myidx, gbase + e + 3);
            float as0 = a_s[(size_t)s0 * H + head];
            float as1 = a_s[(size_t)s1 * H + head];
            float as2 = a_s[(size_t)s2 * H + head];
            float as3 = a_s[(size_t)s3 * H + head];
            uint4 h0 = *(const uint4*)&hb[((size_t)s0 << 7) + c8];
            uint4 h1 = *(const uint4*)&hb[((size_t)s1 << 7) + c8];
            uint4 h2 = *(const uint4*)&hb[((size_t)s2 << 7) + c8];
            uint4 h3 = *(const uint4*)&hb[((size_t)s3 << 7) + c8];
            float p0 = LEAKY_EXP(as0);
            float p1 = LEAKY_EXP(as1);
            float p2 = LEAKY_EXP(as2);
            float p3 = LEAKY_EXP(as3);
            psA += p0;
            psB += p1;
            psA += p2;
            psB += p3;
            ACC8(accA, p0, h0);
            ACC8(accB, p1, h1);
            ACC8(accA, p2, h2);
            ACC8(accB, p3, h3);
        }
        for (; e + 1 < ce; e += 2) {
            int s0 = __shfl(myidx, gbase + e);
            int s1 = __shfl(myidx, gbase + e + 1);
            float as0 = a_s[(size_t)s0 * H + head];
            float as1 = a_s[(size_t)s1 * H + head];
            uint4 h0 = *(const uint4*)&hb[((size_t)s0 << 7) + c8];
            uint4 h1 = *(const uint4*)&hb[((size_t)s1 << 7) + c8];
            float p0 = LEAKY_EXP(as0);
            float p1 = LEAKY_EXP(as1);
            psA += p0;
            psB += p1;
            ACC8(accA, p0, h0);
            ACC8(accB, p1, h1);
        }
        if (e < ce) {
            int s0 = __shfl(myidx, gbase + e);
            float as0 = a_s[(size_t)s0 * H + head];
            uint4 h0 = *(const uint4*)&hb[((size_t)s0 << 7) + c8];
            float p0 = LEAKY_EXP(as0);
            psA += p0;
            ACC8(accA, p0, h0);
        }
    }
#undef ACC8
#undef LEAKY_EXP

    const float inv = 1.0f / (psA + psB + 1e-16f);
    float4 bi0 = *(const float4*)&bias[c8];
    float4 bi1 = *(const float4*)&bias[c8 + 4];
    float val[8];
#pragma unroll
    for (int j = 0; j < 8; ++j) {
        float bj = (j < 4) ? ((const float*)&bi0)[j] : ((const float*)&bi1)[j - 4];
        float v = (accA[j] + accB[j]) * inv + bj;
        val[j] = v > 0.f ? v : (expf(v) - 1.0f);
    }
    if (RES) {
        float4 x0 = *(const float4*)&xprev[((size_t)n << 7) + c8];
        float4 x1 = *(const float4*)&xprev[((size_t)n << 7) + c8 + 4];
        val[0] += x0.x; val[1] += x0.y; val[2] += x0.z; val[3] += x0.w;
        val[4] += x1.x; val[5] += x1.y; val[6] += x1.z; val[7] += x1.w;
    }

    float s1v = 0.f, s2v = 0.f;
#pragma unroll
    for (int j = 0; j < 8; ++j) { s1v += val[j]; s2v += val[j] * val[j]; }
#pragma unroll
    for (int m = 1; m < 16; m <<= 1) {
        s1v += __shfl_xor(s1v, m);
        s2v += __shfl_xor(s2v, m);
    }
    float mu = s1v * (1.0f / 128.0f);
    float var = s2v * (1.0f / 128.0f) - mu * mu;
    float rstd = rsqrtf(var + 1e-5f);
    float4 g0 = *(const float4*)&ln_g[c8];
    float4 g1 = *(const float4*)&ln_g[c8 + 4];
    float4 lb0 = *(const float4*)&ln_b[c8];
    float4 lb1 = *(const float4*)&ln_b[c8 + 4];
    float4 o0, o1;
    o0.x = (val[0] - mu) * rstd * g0.x + lb0.x;
    o0.y = (val[1] - mu) * rstd * g0.y + lb0.y;
    o0.z = (val[2] - mu) * rstd * g0.z + lb0.z;
    o0.w = (val[3] - mu) * rstd * g0.w + lb0.w;
    o1.x = (val[4] - mu) * rstd * g1.x + lb1.x;
    o1.y = (val[5] - mu) * rstd * g1.y + lb1.y;
    o1.z = (val[6] - mu) * rstd * g1.z + lb1.z;
    o1.w = (val[7] - mu) * rstd * g1.w + lb1.w;
    *(float4*)&xout[((size_t)n << 7) + c8] = o0;
    *(float4*)&xout[((size_t)n << 7) + c8 + 4] = o1;
}

// ---------------------------------------------------------------------------
// MFMA prediction MLP.  4 waves/block, 16 rows/wave, 64 rows/block.
// ---------------------------------------------------------------------------
__global__ __launch_bounds__(256) void mlp_mfma_kernel(const float* __restrict__ x,
                                                       const int* __restrict__ uidx,
                                                       const int* __restrict__ vidx,
                                                       int num_users,
                                                       const unsigned short* __restrict__ w1f,
                                                       const float* __restrict__ mb1,
                                                       const unsigned short* __restrict__ w2f,
                                                       const float* __restrict__ mb2,
                                                       const float* __restrict__ mw3,
                                                       const float* __restrict__ mb3,
                                                       float* __restrict__ out, int B) {
    __shared__ unsigned short w1s[32768];
    __shared__ unsigned short w2s[8192];
    __shared__ unsigned short h1s[4][16 * 136];
    const int t = threadIdx.x;
    const int lane = t & 63;
    const int wave = t >> 6;
    const int row0 = blockIdx.x * 64 + wave * 16;
    const int lr = lane & 15;
    const int lk = lane >> 4;

    for (int i = t; i < 4096; i += 256) ((int4*)w1s)[i] = ((const int4*)w1f)[i];
    for (int i = t; i < 1024; i += 256) ((int4*)w2s)[i] = ((const int4*)w2f)[i];

    int b = row0 + lr;
    if (b >= B) b = B - 1;
    const float* urow = &x[(size_t)uidx[b] * 128];
    const float* vrow = &x[(size_t)(vidx[b] + num_users) * 128];
    bf16x8 ahi[8], alo[8];
#pragma unroll
    for (int kk = 0; kk < 8; ++kk) {
        const float* ap = (kk < 4) ? &urow[kk * 32 + lk * 8] : &vrow[(kk - 4) * 32 + lk * 8];
        float4 v0 = *(const float4*)ap;
        float4 v1 = *(const float4*)(ap + 4);
        float f[8] = {v0.x, v0.y, v0.z, v0.w, v1.x, v1.y, v1.z, v1.w};
#pragma unroll
        for (int j = 0; j < 8; ++j) {
            unsigned short hi = f2bf(f[j]);
            unsigned short lo = f2bf(f[j] - bf2f(hi));
            ((short*)&ahi[kk])[j] = (short)hi;
            ((short*)&alo[kk])[j] = (short)lo;
        }
    }

    f32x4 acc[8];
#pragma unroll
    for (int ct = 0; ct < 8; ++ct) acc[ct] = (f32x4){0.f, 0.f, 0.f, 0.f};

    __syncthreads();

#pragma unroll
    for (int kk = 0; kk < 8; ++kk) {
#pragma unroll
        for (int ct = 0; ct < 8; ++ct) {
            const int fo = ((ct * 8 + kk) * 64 + lane) * 8;
            bf16x8 bhi = *(const bf16x8*)&w1s[fo];
            acc[ct] = __builtin_amdgcn_mfma_f32_16x16x32_bf16(ahi[kk], bhi, acc[ct], 0, 0, 0);
            acc[ct] = __builtin_amdgcn_mfma_f32_16x16x32_bf16(alo[kk], bhi, acc[ct], 0, 0, 0);
        }
    }

#pragma unroll
    for (int ct = 0; ct < 8; ++ct) {
        const int col = ct * 16 + lr;
        const float b1 = mb1[col];
#pragma unroll
        for (int r = 0; r < 4; ++r) {
            float v = fmaxf(acc[ct][r] + b1, 0.f);
            h1s[wave][(lk * 4 + r) * 136 + col] = f2bf(v);
        }
    }
    __syncthreads();

    bf16x8 a2[4];
#pragma unroll
    for (int kk = 0; kk < 4; ++kk)
        a2[kk] = *(const bf16x8*)&h1s[wave][lr * 136 + kk * 32 + lk * 8];

    f32x4 acc2[4];
#pragma unroll
    for (int ct = 0; ct < 4; ++ct) acc2[ct] = (f32x4){0.f, 0.f, 0.f, 0.f};
#pragma unroll
    for (int kk = 0; kk < 4; ++kk) {
#pragma unroll
        for (int ct = 0; ct < 4; ++ct) {
            const int fo = ((ct * 4 + kk) * 64 + lane) * 8;
            bf16x8 bhi = *(const bf16x8*)&w2s[fo];
            acc2[ct] = __builtin_amdgcn_mfma_f32_16x16x32_bf16(a2[kk], bhi, acc2[ct], 0, 0, 0);
        }
    }

    float s[4] = {0.f, 0.f, 0.f, 0.f};
#pragma unroll
    for (int ct = 0; ct < 4; ++ct) {
        const int col = ct * 16 + lr;
        const float b2 = mb2[col];
        const float w3 = mw3[col];
#pragma unroll
        for (int r = 0; r < 4; ++r) {
            float v = fmaxf(acc2[ct][r] + b2, 0.f);
            s[r] = fmaf(v, w3, s[r]);
        }
    }
#pragma unroll
    for (int m = 1; m < 16; m <<= 1) {
#pragma unroll
        for (int r = 0; r < 4; ++r) s[r] += __shfl_xor(s[r], m);
    }
    if (lr == 0) {
        const float b3 = mb3[0];
#pragma unroll
        for (int r = 0; r < 4; ++r) {
            int row = row0 + lk * 4 + r;
            if (row < B) out[row] = 1.0f / (1.0f + expf(-(s[r] + b3)));
        }
    }
}

// ---------------------------------------------------------------------------
// launcher
// ---------------------------------------------------------------------------
extern "C" void kernel_launch(void* const* d_in, const int* in_sizes, int n_in,
                              void* d_out, int out_size, void* d_ws, size_t ws_size,
                              hipStream_t stream) {
    const int* uidx = (const int*)d_in[0];
    const int* vidx = (const int*)d_in[1];
    const int* eidx = (const int*)d_in[2];
    const float* utab = (const float*)d_in[3];
    const float* itab = (const float*)d_in[4];
    const float* W0 = (const float*)d_in[5];
    const float* as0 = (const float*)d_in[6];
    const float* ad0 = (const float*)d_in[7];
    const float* bb0 = (const float*)d_in[8];
    const float* W1 = (const float*)d_in[9];
    const float* as1 = (const float*)d_in[10];
    const float* ad1 = (const float*)d_in[11];
    const float* bb1 = (const float*)d_in[12];
    const float* W2 = (const float*)d_in[13];
    const float* as2 = (const float*)d_in[14];
    const float* ad2 = (const float*)d_in[15];
    const float* bb2 = (const float*)d_in[16];
    const float* ln_g = (const float*)d_in[17];
    const float* ln_b = (const float*)d_in[18];
    const float* mw1 = (const float*)d_in[19];
    const float* mb1 = (const float*)d_in[20];
    const float* mw2 = (const float*)d_in[21];
    const float* mb2 = (const float*)d_in[22];
    const float* mw3 = (const float*)d_in[23];
    const float* mb3 = (const float*)d_in[24];

    const int B = in_sizes[0];
    const int E = in_sizes[2] / 2;
    const int num_users = in_sizes[3] / D128;
    const int num_items = in_sizes[4] / D128;
    const int N = num_users + num_items;
    const int* esrc = eidx;
    const int* edst = eidx + E;

    size_t wsoff = 0;
    auto alloc = [&](size_t bytes) {
        void* p = (char*)d_ws + wsoff;
        wsoff += (bytes + 255) & ~(size_t)255;
        return p;
    };
    float* bufA = (float*)alloc((size_t)N * 128 * 4);
    float* bufB = (float*)alloc((size_t)N * 128 * 4);
    unsigned short* hb = (unsigned short*)alloc((size_t)N * 128 * 2);
    float* aS = (float*)alloc((size_t)N * 4 * 4);
    float* aD = (float*)alloc((size_t)N * 4 * 4);
    int* cnt = (int*)alloc((size_t)(N + 1) * 4);
    int* off = (int*)alloc((size_t)(N + 1) * 4);
    int* cur = (int*)alloc((size_t)(N + 1) * 4);
    int* csr_src = (int*)alloc((size_t)E * 4);
    int* partials = (int*)alloc(64 * 4);
    int* pp = (int*)alloc(64 * 4);
    unsigned short* wb0 = (unsigned short*)alloc(2 * 16384 * 2);
    unsigned short* wb1 = (unsigned short*)alloc(2 * 16384 * 2);
    unsigned short* wb2 = (unsigned short*)alloc(2 * 16384 * 2);
    unsigned short* w1f = (unsigned short*)alloc(32768 * 2);
    unsigned short* w2f = (unsigned short*)alloc(8192 * 2);
    (void)ws_size;

    wrepack3_kernel<<<dim3(64, 3), 256, 0, stream>>>(W0, W1, W2, wb0, wb1, wb2);
    wrepack_mlp_kernel<<<dim3(128, 2), 256, 0, stream>>>(mw1, w1f, mw2, w2f);

    const int NB = (N + SCAN_CHUNK - 1) / SCAN_CHUNK;
    zero_int_kernel<<<(N + 255) / 256, 256, 0, stream>>>(cnt, N);
    count_kernel<<<(E + 255) / 256, 256, 0, stream>>>(edst, E, cnt);
    scan_local_kernel<<<NB, SB, 0, stream>>>(cnt, off, partials, N);
    scan_partials_kernel<<<1, 64, 0, stream>>>(partials, pp, NB, off, N);
    scan_add_kernel<<<(N + 255) / 256, 256, 0, stream>>>(off, cur, pp, N);
    fill_kernel<<<(E + 255) / 256, 256, 0, stream>>>(esrc, edst, E, cur, csr_src);

    const int gemm_grid = (N + 127) / 128;
    const int agrid = (N + 15) / 16;

    // ---- layer 0 (H=4, no residual; X = virtual concat of tables) ----
    gemm_mfma_kernel<4, true><<<gemm_grid, 512, 0, stream>>>(utab, itab, num_users, wb0, as0,
                                                             ad0, hb, aS, aD, N);
    agg_kernel<4, false><<<agrid, 256, 0, stream>>>(hb, aS, aD, off, csr_src, nullptr, bb0,
                                                    ln_g, ln_b, bufB, N);
    // ---- layer 1 (H=4, residual) ----
    gemm_mfma_kernel<4, false><<<gemm_grid, 512, 0, stream>>>(bufB, nullptr, 0, wb1, as1, ad1,
                                                              hb, aS, aD, N);
    agg_kernel<4, true><<<agrid, 256, 0, stream>>>(hb, aS, aD, off, csr_src, bufB, bb1, ln_g,
                                                   ln_b, bufA, N);
    // ---- layer 2 (H=1, residual) ----
    gemm_mfma_kernel<1, false><<<gemm_grid, 512, 0, stream>>>(bufA, nullptr, 0, wb2, as2, ad2,
                                                              hb, aS, aD, N);
    agg_kernel<1, true><<<agrid, 256, 0, stream>>>(hb, aS, aD, off, csr_src, bufA, bb2, ln_g,
                                                   ln_b, bufB, N);

    // ---- prediction MLP (MFMA) ----
    mlp_mfma_kernel<<<(B + 63) / 64, 256, 0, stream>>>(bufB, uidx, vidx, num_users, w1f, mb1,
                                                       w2f, mb2, mw3, mb3, (float*)d_out, B);
}

// Round 16
// 234.929 us; speedup vs baseline: 1.0163x; 1.0163x over previous
//
#include <hip/hip_runtime.h>
#include <hip/hip_bf16.h>

#define D128 128
#define NEG_SLOPE 0.2f

typedef __attribute__((ext_vector_type(8))) short bf16x8;
typedef __attribute__((ext_vector_type(4))) float f32x4;

__device__ inline float bf2f(unsigned short u) {
    return __uint_as_float(((unsigned)u) << 16);
}
__device__ inline unsigned short f2bf(float f) {  // RTNE
    unsigned u = __float_as_uint(f);
    unsigned r = (u + 0x7fffu + ((u >> 16) & 1u)) >> 16;
    return (unsigned short)r;
}

// ---------------------------------------------------------------------------
// CSR build
// ---------------------------------------------------------------------------
__global__ void count_kernel(const int* __restrict__ dst, int E, int* __restrict__ cnt) {
    int e = blockIdx.x * blockDim.x + threadIdx.x;
    if (e < E) atomicAdd(&cnt[dst[e]], 1);
}

#define SB 256
#define SCAN_CHUNK 2048  // SB * 8

__global__ __launch_bounds__(SB) void scan_local_kernel(const int* __restrict__ cnt,
                                                        int* __restrict__ off,
                                                        int* __restrict__ partials, int N) {
    __shared__ int lds[SB];
    const int b = blockIdx.x;
    const int t = threadIdx.x;
    const int base = b * SCAN_CHUNK + t * 8;
    int v[8];
    int s = 0;
#pragma unroll
    for (int j = 0; j < 8; ++j) {
        int i = base + j;
        v[j] = (i < N) ? cnt[i] : 0;
        s += v[j];
    }
    lds[t] = s;
    __syncthreads();
    for (int d = 1; d < SB; d <<= 1) {
        int y = (t >= d) ? lds[t - d] : 0;
        __syncthreads();
        lds[t] += y;
        __syncthreads();
    }
    int pref = lds[t] - s;
#pragma unroll
    for (int j = 0; j < 8; ++j) {
        int i = base + j;
        if (i < N) off[i] = pref;
        pref += v[j];
    }
    if (t == SB - 1) partials[b] = lds[t];
}

__global__ __launch_bounds__(64) void scan_partials_kernel(int* __restrict__ partials,
                                                           int* __restrict__ pp, int NB,
                                                           int* __restrict__ off, int N) {
    __shared__ int lds[64];
    int t = threadIdx.x;
    int v = (t < NB) ? partials[t] : 0;
    lds[t] = v;
    __syncthreads();
    for (int d = 1; d < 64; d <<= 1) {
        int y = (t >= d) ? lds[t - d] : 0;
        __syncthreads();
        lds[t] += y;
        __syncthreads();
    }
    pp[t] = lds[t] - v;
    if (t == 63) off[N] = lds[63];
}

__global__ void scan_add_kernel(int* __restrict__ off, int* __restrict__ cur,
                                const int* __restrict__ pp, int N) {
    int i = blockIdx.x * blockDim.x + threadIdx.x;
    if (i < N) {
        int o = off[i] + pp[i / SCAN_CHUNK];
        off[i] = o;
        cur[i] = o;
    }
}

__global__ void fill_kernel(const int* __restrict__ src, const int* __restrict__ dst, int E,
                            int* __restrict__ cur, int* __restrict__ csr_src) {
    int e = blockIdx.x * blockDim.x + threadIdx.x;
    if (e < E) {
        int p = atomicAdd(&cur[dst[e]], 1);
        csr_src[p] = src[e];
    }
}

// ---------------------------------------------------------------------------
// Unified weight repack (one dispatch):
//  y in 0..2: GAT W_y -> split hi/lo bf16 fragments (16384 each + 16384 lo)
//  y == 3:    mw1 [256x128] -> bf16-hi fragments (32768)
//  y == 4:    mw2 [128x64]  -> bf16-hi fragments (8192)
// ---------------------------------------------------------------------------
__global__ __launch_bounds__(256) void wrepack_all_kernel(const float* __restrict__ W0,
                                                          const float* __restrict__ W1,
                                                          const float* __restrict__ W2,
                                                          const float* __restrict__ mw1,
                                                          const float* __restrict__ mw2,
                                                          unsigned short* __restrict__ wb0,
                                                          unsigned short* __restrict__ wb1,
                                                          unsigned short* __restrict__ wb2,
                                                          unsigned short* __restrict__ w1f,
                                                          unsigned short* __restrict__ w2f) {
    const int y = blockIdx.y;
    int i = blockIdx.x * 256 + threadIdx.x;
    if (y < 3) {
        if (i >= 16384) return;
        const float* W = (y == 0) ? W0 : (y == 1) ? W1 : W2;
        unsigned short* Wb = (y == 0) ? wb0 : (y == 1) ? wb1 : wb2;
        int j = i & 7;
        int l = (i >> 3) & 63;
        int kk = (i >> 9) & 3;
        int ct = i >> 11;
        int k = kk * 32 + ((l >> 4) & 3) * 8 + j;
        int c = ct * 16 + (l & 15);
        float w = W[k * 128 + c];
        unsigned short hi = f2bf(w);
        unsigned short lo = f2bf(w - bf2f(hi));
        Wb[i] = hi;
        Wb[16384 + i] = lo;
    } else {
        const float* W = (y == 3) ? mw1 : mw2;
        unsigned short* Wf = (y == 3) ? w1f : w2f;
        const int K = (y == 3) ? 256 : 128, C = (y == 3) ? 128 : 64;
        if (i >= K * C) return;
        int j = i & 7;
        int l = (i >> 3) & 63;
        int kkct = i >> 9;
        int KK = K >> 5;
        int kk = kkct % KK;
        int ct = kkct / KK;
        int k = kk * 32 + (l >> 4) * 8 + j;
        int c = ct * 16 + (l & 15);
        Wf[i] = f2bf(W[k * C + c]);
    }
}

// ---------------------------------------------------------------------------
// MFMA GEMM (split-bf16 ~ fp32 accuracy) fused with attention scalars.
// 8 waves/block, 128 rows/block, W fragments staged in LDS.
// ---------------------------------------------------------------------------
template <int H, bool SPLIT>
__global__ __launch_bounds__(512) void gemm_mfma_kernel(const float* __restrict__ X0,
                                                        const float* __restrict__ X1, int split,
                                                        const unsigned short* __restrict__ Wb,
                                                        const float* __restrict__ att_s,
                                                        const float* __restrict__ att_d,
                                                        unsigned short* __restrict__ hb,
                                                        float* __restrict__ a_s,
                                                        float* __restrict__ a_d, int N) {
    __shared__ unsigned short wlds[32768];  // 64 KB: hi [0,16384), lo [16384,32768)
    const int t = threadIdx.x;
    const int lane = t & 63;
    const int wave = t >> 6;
    const int row0 = blockIdx.x * 128 + wave * 16;

    for (int i = t; i < 4096; i += 512)
        ((int4*)wlds)[i] = ((const int4*)Wb)[i];

    const int lr = lane & 15;
    const int lk = lane >> 4;

    int arow = row0 + lr;
    if (arow >= N) arow = N - 1;  // clamp; padded rows never stored
    const float* xrow;
    if (SPLIT)
        xrow = (arow < split) ? &X0[(size_t)arow * 128] : &X1[(size_t)(arow - split) * 128];
    else
        xrow = &X0[(size_t)arow * 128];

    bf16x8 ahi[4], alo[4];
#pragma unroll
    for (int kk = 0; kk < 4; ++kk) {
        const float* ap = &xrow[kk * 32 + lk * 8];
        float4 v0 = *(const float4*)ap;
        float4 v1 = *(const float4*)(ap + 4);
        float f[8] = {v0.x, v0.y, v0.z, v0.w, v1.x, v1.y, v1.z, v1.w};
#pragma unroll
        for (int j = 0; j < 8; ++j) {
            unsigned short hi = f2bf(f[j]);
            unsigned short lo = f2bf(f[j] - bf2f(hi));
            ((short*)&ahi[kk])[j] = (short)hi;
            ((short*)&alo[kk])[j] = (short)lo;
        }
    }

    f32x4 acc[8];
#pragma unroll
    for (int ct = 0; ct < 8; ++ct) acc[ct] = (f32x4){0.f, 0.f, 0.f, 0.f};

    __syncthreads();

#pragma unroll
    for (int kk = 0; kk < 4; ++kk) {
#pragma unroll
        for (int ct = 0; ct < 8; ++ct) {
            const int fo = ((ct * 4 + kk) * 64 + lane) * 8;
            bf16x8 bhi = *(const bf16x8*)&wlds[fo];
            bf16x8 blo = *(const bf16x8*)&wlds[16384 + fo];
            acc[ct] = __builtin_amdgcn_mfma_f32_16x16x32_bf16(ahi[kk], bhi, acc[ct], 0, 0, 0);
            acc[ct] = __builtin_amdgcn_mfma_f32_16x16x32_bf16(ahi[kk], blo, acc[ct], 0, 0, 0);
            acc[ct] = __builtin_amdgcn_mfma_f32_16x16x32_bf16(alo[kk], bhi, acc[ct], 0, 0, 0);
        }
    }

    float ps[4][H], pd[4][H];
#pragma unroll
    for (int r = 0; r < 4; ++r)
#pragma unroll
        for (int h = 0; h < H; ++h) { ps[r][h] = 0.f; pd[r][h] = 0.f; }

#pragma unroll
    for (int ct = 0; ct < 8; ++ct) {
        float as_c = att_s[ct * 16 + lr];
        float ad_c = att_d[ct * 16 + lr];
        const int h = (ct * H) >> 3;
#pragma unroll
        for (int r = 0; r < 4; ++r) {
            float v = acc[ct][r];
            int row = row0 + lk * 4 + r;
            if (row < N) hb[(size_t)row * 128 + ct * 16 + lr] = f2bf(v);
            ps[r][h] += v * as_c;
            pd[r][h] += v * ad_c;
        }
    }

#pragma unroll
    for (int m = 1; m < 16; m <<= 1) {
#pragma unroll
        for (int r = 0; r < 4; ++r)
#pragma unroll
            for (int h = 0; h < H; ++h) {
                ps[r][h] += __shfl_xor(ps[r][h], m);
                pd[r][h] += __shfl_xor(pd[r][h], m);
            }
    }
    if (lr == 0) {
#pragma unroll
        for (int r = 0; r < 4; ++r) {
            int row = row0 + lk * 4 + r;
            if (row < N) {
                if (H == 4) {
                    *(float4*)&a_s[(size_t)row * 4] =
                        make_float4(ps[r][0], ps[r][1], ps[r][2], ps[r][3]);
                    *(float4*)&a_d[(size_t)row * 4] =
                        make_float4(pd[r][0], pd[r][1], pd[r][2], pd[r][3]);
                } else {
                    a_s[row] = ps[r][0];
                    a_d[row] = pd[r][0];
                }
            }
        }
    }
}

// ---------------------------------------------------------------------------
// aggregation + bias + ELU + residual + LayerNorm, softmax numerator inline.
// CHANNEL-SPLIT: 16 lanes per node (8 channels, dwordx4 gathers), 4 nodes
// per wave, 16 nodes per 256-thr block.  2-way edge unroll (best measured:
// VGPR 28, ~62% occupancy; 4-deep raises VGPR to 44 and is net-neutral).
// ---------------------------------------------------------------------------
template <int H, bool RES>
__global__ __launch_bounds__(256) void agg_kernel(const unsigned short* __restrict__ hb,
                                                  const float* __restrict__ a_s,
                                                  const float* __restrict__ a_d,
                                                  const int* __restrict__ off,
                                                  const int* __restrict__ csr_src,
                                                  const float* __restrict__ xprev,
                                                  const float* __restrict__ bias,
                                                  const float* __restrict__ ln_g,
                                                  const float* __restrict__ ln_b,
                                                  float* __restrict__ xout, int N) {
    const int t = threadIdx.x;
    const int l16 = t & 15;                 // lane within node group
    const int gbase = t & 48;               // group's base lane within wave
    const int n = blockIdx.x * 16 + (t >> 4);
    if (n >= N) return;
    const int c8 = l16 * 8;                 // first of this lane's 8 channels
    const int head = (c8 * H) >> 7;         // c8 / (128/H)
    const int base = off[n];
    const int deg = off[n + 1] - base;
    const float adn = a_d[(size_t)n * H + head];

    float accA[8], accB[8];
#pragma unroll
    for (int j = 0; j < 8; ++j) { accA[j] = 0.f; accB[j] = 0.f; }
    float psA = 0.f, psB = 0.f;

#define ACC8(ACC, P, HV)                                                     \
    ACC[0] = fmaf(P, bf2f((unsigned short)HV.x), ACC[0]);                    \
    ACC[1] = fmaf(P, bf2f((unsigned short)(HV.x >> 16)), ACC[1]);            \
    ACC[2] = fmaf(P, bf2f((unsigned short)HV.y), ACC[2]);                    \
    ACC[3] = fmaf(P, bf2f((unsigned short)(HV.y >> 16)), ACC[3]);            \
    ACC[4] = fmaf(P, bf2f((unsigned short)HV.z), ACC[4]);                    \
    ACC[5] = fmaf(P, bf2f((unsigned short)(HV.z >> 16)), ACC[5]);            \
    ACC[6] = fmaf(P, bf2f((unsigned short)HV.w), ACC[6]);                    \
    ACC[7] = fmaf(P, bf2f((unsigned short)(HV.w >> 16)), ACC[7]);

    for (int e0 = 0; e0 < deg; e0 += 16) {
        const int ce = min(16, deg - e0);
        int myidx = 0;
        if (l16 < ce) myidx = csr_src[base + e0 + l16];
        int e = 0;
        for (; e + 1 < ce; e += 2) {
            int s0 = __shfl(myidx, gbase + e);
            int s1 = __shfl(myidx, gbase + e + 1);
            float as0 = a_s[(size_t)s0 * H + head];
            float as1 = a_s[(size_t)s1 * H + head];
            uint4 h0 = *(const uint4*)&hb[((size_t)s0 << 7) + c8];
            uint4 h1 = *(const uint4*)&hb[((size_t)s1 << 7) + c8];
            float lg0 = as0 + adn;
            lg0 = lg0 >= 0.f ? lg0 : NEG_SLOPE * lg0;
            float p0 = expf(lg0);
            float lg1 = as1 + adn;
            lg1 = lg1 >= 0.f ? lg1 : NEG_SLOPE * lg1;
            float p1 = expf(lg1);
            psA += p0;
            psB += p1;
            ACC8(accA, p0, h0);
            ACC8(accB, p1, h1);
        }
        if (e < ce) {
            int s0 = __shfl(myidx, gbase + e);
            float as0 = a_s[(size_t)s0 * H + head];
            uint4 h0 = *(const uint4*)&hb[((size_t)s0 << 7) + c8];
            float lg0 = as0 + adn;
            lg0 = lg0 >= 0.f ? lg0 : NEG_SLOPE * lg0;
            float p0 = expf(lg0);
            psA += p0;
            ACC8(accA, p0, h0);
        }
    }
#undef ACC8

    const float inv = 1.0f / (psA + psB + 1e-16f);
    float4 bi0 = *(const float4*)&bias[c8];
    float4 bi1 = *(const float4*)&bias[c8 + 4];
    float val[8];
#pragma unroll
    for (int j = 0; j < 8; ++j) {
        float bj = (j < 4) ? ((const float*)&bi0)[j] : ((const float*)&bi1)[j - 4];
        float v = (accA[j] + accB[j]) * inv + bj;
        val[j] = v > 0.f ? v : (expf(v) - 1.0f);
    }
    if (RES) {
        float4 x0 = *(const float4*)&xprev[((size_t)n << 7) + c8];
        float4 x1 = *(const float4*)&xprev[((size_t)n << 7) + c8 + 4];
        val[0] += x0.x; val[1] += x0.y; val[2] += x0.z; val[3] += x0.w;
        val[4] += x1.x; val[5] += x1.y; val[6] += x1.z; val[7] += x1.w;
    }

    float s1v = 0.f, s2v = 0.f;
#pragma unroll
    for (int j = 0; j < 8; ++j) { s1v += val[j]; s2v += val[j] * val[j]; }
#pragma unroll
    for (int m = 1; m < 16; m <<= 1) {
        s1v += __shfl_xor(s1v, m);
        s2v += __shfl_xor(s2v, m);
    }
    float mu = s1v * (1.0f / 128.0f);
    float var = s2v * (1.0f / 128.0f) - mu * mu;
    float rstd = rsqrtf(var + 1e-5f);
    float4 g0 = *(const float4*)&ln_g[c8];
    float4 g1 = *(const float4*)&ln_g[c8 + 4];
    float4 lb0 = *(const float4*)&ln_b[c8];
    float4 lb1 = *(const float4*)&ln_b[c8 + 4];
    float4 o0, o1;
    o0.x = (val[0] - mu) * rstd * g0.x + lb0.x;
    o0.y = (val[1] - mu) * rstd * g0.y + lb0.y;
    o0.z = (val[2] - mu) * rstd * g0.z + lb0.z;
    o0.w = (val[3] - mu) * rstd * g0.w + lb0.w;
    o1.x = (val[4] - mu) * rstd * g1.x + lb1.x;
    o1.y = (val[5] - mu) * rstd * g1.y + lb1.y;
    o1.z = (val[6] - mu) * rstd * g1.z + lb1.z;
    o1.w = (val[7] - mu) * rstd * g1.w + lb1.w;
    *(float4*)&xout[((size_t)n << 7) + c8] = o0;
    *(float4*)&xout[((size_t)n << 7) + c8 + 4] = o1;
}

// ---------------------------------------------------------------------------
// MFMA prediction MLP.  4 waves/block, 16 rows/wave, 64 rows/block.
// ---------------------------------------------------------------------------
__global__ __launch_bounds__(256) void mlp_mfma_kernel(const float* __restrict__ x,
                                                       const int* __restrict__ uidx,
                                                       const int* __restrict__ vidx,
                                                       int num_users,
                                                       const unsigned short* __restrict__ w1f,
                                                       const float* __restrict__ mb1,
                                                       const unsigned short* __restrict__ w2f,
                                                       const float* __restrict__ mb2,
                                                       const float* __restrict__ mw3,
                                                       const float* __restrict__ mb3,
                                                       float* __restrict__ out, int B) {
    __shared__ unsigned short w1s[32768];
    __shared__ unsigned short w2s[8192];
    __shared__ unsigned short h1s[4][16 * 136];
    const int t = threadIdx.x;
    const int lane = t & 63;
    const int wave = t >> 6;
    const int row0 = blockIdx.x * 64 + wave * 16;
    const int lr = lane & 15;
    const int lk = lane >> 4;

    for (int i = t; i < 4096; i += 256) ((int4*)w1s)[i] = ((const int4*)w1f)[i];
    for (int i = t; i < 1024; i += 256) ((int4*)w2s)[i] = ((const int4*)w2f)[i];

    int b = row0 + lr;
    if (b >= B) b = B - 1;
    const float* urow = &x[(size_t)uidx[b] * 128];
    const float* vrow = &x[(size_t)(vidx[b] + num_users) * 128];
    bf16x8 ahi[8], alo[8];
#pragma unroll
    for (int kk = 0; kk < 8; ++kk) {
        const float* ap = (kk < 4) ? &urow[kk * 32 + lk * 8] : &vrow[(kk - 4) * 32 + lk * 8];
        float4 v0 = *(const float4*)ap;
        float4 v1 = *(const float4*)(ap + 4);
        float f[8] = {v0.x, v0.y, v0.z, v0.w, v1.x, v1.y, v1.z, v1.w};
#pragma unroll
        for (int j = 0; j < 8; ++j) {
            unsigned short hi = f2bf(f[j]);
            unsigned short lo = f2bf(f[j] - bf2f(hi));
            ((short*)&ahi[kk])[j] = (short)hi;
            ((short*)&alo[kk])[j] = (short)lo;
        }
    }

    f32x4 acc[8];
#pragma unroll
    for (int ct = 0; ct < 8; ++ct) acc[ct] = (f32x4){0.f, 0.f, 0.f, 0.f};

    __syncthreads();

#pragma unroll
    for (int kk = 0; kk < 8; ++kk) {
#pragma unroll
        for (int ct = 0; ct < 8; ++ct) {
            const int fo = ((ct * 8 + kk) * 64 + lane) * 8;
            bf16x8 bhi = *(const bf16x8*)&w1s[fo];
            acc[ct] = __builtin_amdgcn_mfma_f32_16x16x32_bf16(ahi[kk], bhi, acc[ct], 0, 0, 0);
            acc[ct] = __builtin_amdgcn_mfma_f32_16x16x32_bf16(alo[kk], bhi, acc[ct], 0, 0, 0);
        }
    }

#pragma unroll
    for (int ct = 0; ct < 8; ++ct) {
        const int col = ct * 16 + lr;
        const float b1 = mb1[col];
#pragma unroll
        for (int r = 0; r < 4; ++r) {
            float v = fmaxf(acc[ct][r] + b1, 0.f);
            h1s[wave][(lk * 4 + r) * 136 + col] = f2bf(v);
        }
    }
    __syncthreads();

    bf16x8 a2[4];
#pragma unroll
    for (int kk = 0; kk < 4; ++kk)
        a2[kk] = *(const bf16x8*)&h1s[wave][lr * 136 + kk * 32 + lk * 8];

    f32x4 acc2[4];
#pragma unroll
    for (int ct = 0; ct < 4; ++ct) acc2[ct] = (f32x4){0.f, 0.f, 0.f, 0.f};
#pragma unroll
    for (int kk = 0; kk < 4; ++kk) {
#pragma unroll
        for (int ct = 0; ct < 4; ++ct) {
            const int fo = ((ct * 4 + kk) * 64 + lane) * 8;
            bf16x8 bhi = *(const bf16x8*)&w2s[fo];
            acc2[ct] = __builtin_amdgcn_mfma_f32_16x16x32_bf16(a2[kk], bhi, acc2[ct], 0, 0, 0);
        }
    }

    float s[4] = {0.f, 0.f, 0.f, 0.f};
#pragma unroll
    for (int ct = 0; ct < 4; ++ct) {
        const int col = ct * 16 + lr;
        const float b2 = mb2[col];
        const float w3 = mw3[col];
#pragma unroll
        for (int r = 0; r < 4; ++r) {
            float v = fmaxf(acc2[ct][r] + b2, 0.f);
            s[r] = fmaf(v, w3, s[r]);
        }
    }
#pragma unroll
    for (int m = 1; m < 16; m <<= 1) {
#pragma unroll
        for (int r = 0; r < 4; ++r) s[r] += __shfl_xor(s[r], m);
    }
    if (lr == 0) {
        const float b3 = mb3[0];
#pragma unroll
        for (int r = 0; r < 4; ++r) {
            int row = row0 + lk * 4 + r;
            if (row < B) out[row] = 1.0f / (1.0f + expf(-(s[r] + b3)));
        }
    }
}

// ---------------------------------------------------------------------------
// launcher
// ---------------------------------------------------------------------------
extern "C" void kernel_launch(void* const* d_in, const int* in_sizes, int n_in,
                              void* d_out, int out_size, void* d_ws, size_t ws_size,
                              hipStream_t stream) {
    const int* uidx = (const int*)d_in[0];
    const int* vidx = (const int*)d_in[1];
    const int* eidx = (const int*)d_in[2];
    const float* utab = (const float*)d_in[3];
    const float* itab = (const float*)d_in[4];
    const float* W0 = (const float*)d_in[5];
    const float* as0 = (const float*)d_in[6];
    const float* ad0 = (const float*)d_in[7];
    const float* bb0 = (const float*)d_in[8];
    const float* W1 = (const float*)d_in[9];
    const float* as1 = (const float*)d_in[10];
    const float* ad1 = (const float*)d_in[11];
    const float* bb1 = (const float*)d_in[12];
    const float* W2 = (const float*)d_in[13];
    const float* as2 = (const float*)d_in[14];
    const float* ad2 = (const float*)d_in[15];
    const float* bb2 = (const float*)d_in[16];
    const float* ln_g = (const float*)d_in[17];
    const float* ln_b = (const float*)d_in[18];
    const float* mw1 = (const float*)d_in[19];
    const float* mb1 = (const float*)d_in[20];
    const float* mw2 = (const float*)d_in[21];
    const float* mb2 = (const float*)d_in[22];
    const float* mw3 = (const float*)d_in[23];
    const float* mb3 = (const float*)d_in[24];

    const int B = in_sizes[0];
    const int E = in_sizes[2] / 2;
    const int num_users = in_sizes[3] / D128;
    const int num_items = in_sizes[4] / D128;
    const int N = num_users + num_items;
    const int* esrc = eidx;
    const int* edst = eidx + E;

    size_t wsoff = 0;
    auto alloc = [&](size_t bytes) {
        void* p = (char*)d_ws + wsoff;
        wsoff += (bytes + 255) & ~(size_t)255;
        return p;
    };
    float* bufA = (float*)alloc((size_t)N * 128 * 4);
    float* bufB = (float*)alloc((size_t)N * 128 * 4);
    unsigned short* hb = (unsigned short*)alloc((size_t)N * 128 * 2);
    float* aS = (float*)alloc((size_t)N * 4 * 4);
    float* aD = (float*)alloc((size_t)N * 4 * 4);
    int* cnt = (int*)alloc((size_t)(N + 1) * 4);
    int* off = (int*)alloc((size_t)(N + 1) * 4);
    int* cur = (int*)alloc((size_t)(N + 1) * 4);
    int* csr_src = (int*)alloc((size_t)E * 4);
    int* partials = (int*)alloc(64 * 4);
    int* pp = (int*)alloc(64 * 4);
    unsigned short* wb0 = (unsigned short*)alloc(2 * 16384 * 2);
    unsigned short* wb1 = (unsigned short*)alloc(2 * 16384 * 2);
    unsigned short* wb2 = (unsigned short*)alloc(2 * 16384 * 2);
    unsigned short* w1f = (unsigned short*)alloc(32768 * 2);
    unsigned short* w2f = (unsigned short*)alloc(8192 * 2);
    (void)ws_size;

    // all weight repacks in one dispatch
    wrepack_all_kernel<<<dim3(128, 5), 256, 0, stream>>>(W0, W1, W2, mw1, mw2, wb0, wb1, wb2,
                                                         w1f, w2f);

    const int NB = (N + SCAN_CHUNK - 1) / SCAN_CHUNK;
    hipMemsetAsync(cnt, 0, (size_t)N * 4, stream);
    count_kernel<<<(E + 255) / 256, 256, 0, stream>>>(edst, E, cnt);
    scan_local_kernel<<<NB, SB, 0, stream>>>(cnt, off, partials, N);
    scan_partials_kernel<<<1, 64, 0, stream>>>(partials, pp, NB, off, N);
    scan_add_kernel<<<(N + 255) / 256, 256, 0, stream>>>(off, cur, pp, N);
    fill_kernel<<<(E + 255) / 256, 256, 0, stream>>>(esrc, edst, E, cur, csr_src);

    const int gemm_grid = (N + 127) / 128;
    const int agrid = (N + 15) / 16;

    // ---- layer 0 (H=4, no residual; X = virtual concat of tables) ----
    gemm_mfma_kernel<4, true><<<gemm_grid, 512, 0, stream>>>(utab, itab, num_users, wb0, as0,
                                                             ad0, hb, aS, aD, N);
    agg_kernel<4, false><<<agrid, 256, 0, stream>>>(hb, aS, aD, off, csr_src, nullptr, bb0,
                                                    ln_g, ln_b, bufB, N);
    // ---- layer 1 (H=4, residual) ----
    gemm_mfma_kernel<4, false><<<gemm_grid, 512, 0, stream>>>(bufB, nullptr, 0, wb1, as1, ad1,
                                                              hb, aS, aD, N);
    agg_kernel<4, true><<<agrid, 256, 0, stream>>>(hb, aS, aD, off, csr_src, bufB, bb1, ln_g,
                                                   ln_b, bufA, N);
    // ---- layer 2 (H=1, residual) ----
    gemm_mfma_kernel<1, false><<<gemm_grid, 512, 0, stream>>>(bufA, nullptr, 0, wb2, as2, ad2,
                                                              hb, aS, aD, N);
    agg_kernel<1, true><<<agrid, 256, 0, stream>>>(hb, aS, aD, off, csr_src, bufA, bb2, ln_g,
                                                   ln_b, bufB, N);

    // ---- prediction MLP (MFMA) ----
    mlp_mfma_kernel<<<(B + 63) / 64, 256, 0, stream>>>(bufB, uidx, vidx, num_users, w1f, mb1,
                                                       w2f, mb2, mw3, mb3, (float*)d_out, B);
}